// Round 10
// baseline (147.692 us; speedup 1.0000x reference)
//
#include <hip/hip_runtime.h>
#include <hip/hip_bf16.h>

#define T_ 4096
#define C_ 1024
#define H_ 64
#define LSTR 72    // P-buffer LDS row stride (bf16 elems)
#define XBS 1032   // x-tile LDS row stride (bf16 elems)

typedef short bf16x8 __attribute__((ext_vector_type(8)));
typedef float f32x4 __attribute__((ext_vector_type(4)));

__device__ __forceinline__ short f2bf(float f) {
  union { __hip_bfloat16 h; short s; } u;
  u.h = __float2bfloat16(f);
  return u.s;
}
__device__ __forceinline__ unsigned pack2(float a, float b) {
  return ((unsigned)(unsigned short)f2bf(b) << 16) | (unsigned short)f2bf(a);
}

// ---- kernel 0: W[c][h] fp32 -> Wtf in MFMA B-FRAG ORDER (R9-verified).
__global__ void wtrans_kernel(const float* __restrict__ Wk,
                              const float* __restrict__ Wq,
                              const float* __restrict__ Wv,
                              __hip_bfloat16* __restrict__ Wtf) {
  int tid = blockIdx.x * 256 + threadIdx.x;  // 0..196607 exact
  const int j = tid & 7;
  const int lane = (tid >> 3) & 63;
  const int m = lane & 15;
  const int quad = lane >> 4;
  const int f = (tid >> 9) & 15;
  const int nt = f & 3;
  const int ks = f >> 2;
  const int c = (tid >> 13) & 7;
  const int which = tid >> 16;
  const float* W = (which == 0) ? Wk : ((which == 1) ? Wq : Wv);
  const int cc = c * 128 + ks * 32 + quad * 8 + j;
  const int h = nt * 16 + m;
  Wtf[tid] = __float2bfloat16(W[cc * 64 + h]);
}

// ---- kernel 1: qkv projection v3 (R9, verified; ~28us). Unchanged.
__global__ __launch_bounds__(256) void proj_kernel(
    const float* __restrict__ x, const __hip_bfloat16* __restrict__ Wtf,
    __hip_bfloat16* __restrict__ qb, __hip_bfloat16* __restrict__ Kf,
    __hip_bfloat16* __restrict__ Vf) {
  __shared__ __hip_bfloat16 Xb[16 * XBS];
  const int tid = threadIdx.x;
  const int lane = tid & 63;
  const int wave = tid >> 6;
  const int m = lane & 15;
  const int quad = lane >> 4;
  const int t0 = blockIdx.x * 16;

  const float4* xtile = (const float4*)(x + (size_t)t0 * C_);
  float4 xv[16];
#pragma unroll
  for (int k = 0; k < 16; ++k) xv[k] = xtile[tid + k * 256];
#pragma unroll
  for (int k = 0; k < 16; ++k) {
    const int idx = tid + k * 256;
    const int row = idx >> 8;
    const int c4 = idx & 255;
    uint2 u = {pack2(xv[k].x, xv[k].y), pack2(xv[k].z, xv[k].w)};
    *(uint2*)(&Xb[row * XBS + c4 * 4]) = u;
  }
  __syncthreads();

  int whichs[3], ntls[3];
  const __hip_bfloat16* wb[3];
#pragma unroll
  for (int i = 0; i < 3; ++i) {
    const int g = wave * 3 + i;
    whichs[i] = g >> 2;
    ntls[i] = g & 3;
    wb[i] = Wtf + (size_t)whichs[i] * 65536 + ntls[i] * 512 + lane * 8;
  }
  f32x4 acc[3];
#pragma unroll
  for (int i = 0; i < 3; ++i) acc[i] = (f32x4){0.f, 0.f, 0.f, 0.f};

#pragma unroll
  for (int c = 0; c < 8; ++c) {
    bf16x8 bq[12];
#pragma unroll
    for (int i = 0; i < 3; ++i)
#pragma unroll
      for (int ks = 0; ks < 4; ++ks)
        bq[i * 4 + ks] = *(const bf16x8*)(wb[i] + (c * 16 + ks * 4) * 512);
#pragma unroll
    for (int ks = 0; ks < 4; ++ks) {
      bf16x8 a = *(const bf16x8*)(&Xb[m * XBS + c * 128 + ks * 32 + quad * 8]);
#pragma unroll
      for (int i = 0; i < 3; ++i)
        acc[i] = __builtin_amdgcn_mfma_f32_16x16x32_bf16(a, bq[i * 4 + ks],
                                                         acc[i], 0, 0, 0);
    }
  }

  const int bb = t0 >> 12;
  const int tloc = t0 & (T_ - 1);
  const int ktile = tloc >> 6;
  const float cscale = 0.18033688011112042f;  // log2(e)/sqrt(64)

#pragma unroll
  for (int i = 0; i < 3; ++i) {
    const int which = whichs[i];
    const int ntl = ntls[i];
    if (which == 1) {
#pragma unroll
      for (int r = 0; r < 4; ++r)
        qb[(size_t)(t0 + quad * 4 + r) * H_ + ntl * 16 + m] =
            __float2bfloat16(acc[i][r] * cscale);
    } else if (which == 0) {
      __hip_bfloat16* dst = Kf + ((size_t)bb * 64 + ktile) * 4096;
      const int ntK = (tloc >> 4) & 3;
      const int wh = ntl >> 1;
      const int quadK = (ntl * 2 + (m >> 3)) & 3;
      const int j = m & 7;
#pragma unroll
      for (int r = 0; r < 4; ++r) {
        const int mK = quad * 4 + r;
        dst[(ntK * 2 + wh) * 512 + (quadK * 16 + mK) * 8 + j] =
            __float2bfloat16(acc[i][r]);
      }
    } else {
      __hip_bfloat16* dst = Vf + ((size_t)bb * 64 + ktile) * 4096;
#pragma unroll
      for (int r = 0; r < 4; ++r) {
        const int kvo = (tloc & 63) + quad * 4 + r;
        const int half = (kvo >> 5) & 1;
        const int quadV = (kvo >> 3) & 3;
        const int j = kvo & 7;
        dst[(ntl * 2 + half) * 512 + (quadV * 16 + m) * 8 + j] =
            __float2bfloat16(acc[i][r]);
      }
    }
  }
}

// ---- kernel 2: flash pass1 v3: S^T + static-max (R8) + P double-buffer +
// next-tile K prefetch + atomicAdd outputs (no Opart round-trip).
__global__ __launch_bounds__(256, 3) void fa_pass1(
    const __hip_bfloat16* __restrict__ qg, const __hip_bfloat16* __restrict__ Kf,
    const __hip_bfloat16* __restrict__ Vf, float* __restrict__ Ofin,
    float* __restrict__ Lfin) {
  __shared__ __hip_bfloat16 Pl[4][2][16 * LSTR];  // double-buffered per wave
  const int lane = threadIdx.x & 63;
  const int wave = threadIdx.x >> 6;
  const int m = lane & 15;
  const int quad = lane >> 4;

  const int jid = blockIdx.x * 4 + wave;  // 0..4607
  const int b = jid / 1152;
  const int j2 = jid - b * 1152;
  int g = 7;
  while (16 * g * (g + 1) > j2) --g;
  const int r2 = j2 - 16 * g * (g + 1);
  const int qt = 32 * g + r2 / (g + 1);
  const int c = r2 - (r2 / (g + 1)) * (g + 1);
  const int q0 = qt * 16;
  const int k0s = c * 512;
  const int kend0 = k0s + 512;
  const int kend = (kend0 < q0 + 16) ? kend0 : (q0 + 16);
  const int ntile = (kend - k0s + 63) >> 6;
  const int kt0 = k0s >> 6;

  const __hip_bfloat16* qbase = qg + ((size_t)b * T_ + q0 + m) * H_;
  bf16x8 qf0 = *(const bf16x8*)(qbase + quad * 8);
  bf16x8 qf1 = *(const bf16x8*)(qbase + 32 + quad * 8);

  f32x4 Oacc[4];
#pragma unroll
  for (int i = 0; i < 4; ++i) Oacc[i] = (f32x4){0.f, 0.f, 0.f, 0.f};
  float psum = 0.f;

  const __hip_bfloat16* kgf = Kf + (size_t)b * 262144 + lane * 8;
  const __hip_bfloat16* vgf = Vf + (size_t)b * 262144 + lane * 8;

  // prologue: K frags of tile 0
  bf16x8 kf[8];
  {
    const __hip_bfloat16* kp = kgf + (size_t)kt0 * 4096;
#pragma unroll
    for (int nt = 0; nt < 4; ++nt) {
      kf[2 * nt] = *(const bf16x8*)(kp + nt * 1024);
      kf[2 * nt + 1] = *(const bf16x8*)(kp + nt * 1024 + 512);
    }
  }

  for (int it = 0; it < ntile; ++it) {
    const int ktile = kt0 + it;
    const int k0 = ktile * 64;
    const __hip_bfloat16* vp = vgf + (size_t)ktile * 4096;

    // issue V (current) and K (next tile) loads up front
    bf16x8 vf[8];
#pragma unroll
    for (int nt = 0; nt < 4; ++nt) {
      vf[2 * nt] = *(const bf16x8*)(vp + nt * 1024);
      vf[2 * nt + 1] = *(const bf16x8*)(vp + nt * 1024 + 512);
    }
    const int ktn = (it + 1 < ntile) ? (ktile + 1) : ktile;  // in-bounds dummy on last
    const __hip_bfloat16* kpn = kgf + (size_t)ktn * 4096;
    bf16x8 kn[8];
#pragma unroll
    for (int nt = 0; nt < 4; ++nt) {
      kn[2 * nt] = *(const bf16x8*)(kpn + nt * 1024);
      kn[2 * nt + 1] = *(const bf16x8*)(kpn + nt * 1024 + 512);
    }

    // S^T = K Q^T (kf resident since previous iteration)
    f32x4 s[4];
#pragma unroll
    for (int nt = 0; nt < 4; ++nt) {
      f32x4 t = (f32x4){0.f, 0.f, 0.f, 0.f};
      t = __builtin_amdgcn_mfma_f32_16x16x32_bf16(kf[2 * nt], qf0, t, 0, 0, 0);
      t = __builtin_amdgcn_mfma_f32_16x16x32_bf16(kf[2 * nt + 1], qf1, t, 0, 0, 0);
      s[nt] = t;
    }

    __hip_bfloat16* Plw = &Pl[wave][it & 1][0];
    const bool needmask = (k0 + 63 > q0);
#pragma unroll
    for (int nt = 0; nt < 4; ++nt) {
      float p[4];
#pragma unroll
      for (int r = 0; r < 4; ++r) {
        float sv = s[nt][r];
        if (needmask && (k0 + nt * 16 + quad * 4 + r) > (q0 + m))
          sv = -__builtin_inff();
        p[r] = exp2f(sv);
        psum += p[r];
      }
      uint2 u = {pack2(p[0], p[1]), pack2(p[2], p[3])};
      *(uint2*)(&Plw[m * LSTR + nt * 16 + quad * 4]) = u;
    }

    bf16x8 pf0 = *(const bf16x8*)(&Plw[m * LSTR + quad * 8]);
    bf16x8 pf1 = *(const bf16x8*)(&Plw[m * LSTR + 32 + quad * 8]);
#pragma unroll
    for (int nt = 0; nt < 4; ++nt) {
      Oacc[nt] = __builtin_amdgcn_mfma_f32_16x16x32_bf16(pf0, vf[2 * nt], Oacc[nt], 0, 0, 0);
      Oacc[nt] = __builtin_amdgcn_mfma_f32_16x16x32_bf16(pf1, vf[2 * nt + 1], Oacc[nt], 0, 0, 0);
    }
#pragma unroll
    for (int i = 0; i < 8; ++i) kf[i] = kn[i];
  }

  psum += __shfl_xor(psum, 16);
  psum += __shfl_xor(psum, 32);

  // accumulate partials directly (device-scope f32 atomics; <=8-way contention)
  float* Og = Ofin + ((size_t)b * T_ + q0) * 64;
#pragma unroll
  for (int nt = 0; nt < 4; ++nt)
#pragma unroll
    for (int r = 0; r < 4; ++r)
      atomicAdd(&Og[(quad * 4 + r) * 64 + nt * 16 + m], Oacc[nt][r]);
  if (lane < 16) atomicAdd(&Lfin[(size_t)b * T_ + q0 + lane], psum);
}

// ---- kernel 3: normalize. out = Ofin / Lfin (coalesced float4 stream).
__global__ __launch_bounds__(256) void fa_norm(
    const float* __restrict__ Ofin, const float* __restrict__ Lfin,
    float* __restrict__ out) {
  const int idx = blockIdx.x * 256 + threadIdx.x;  // 0..262143 float4s
  const int row = idx >> 4;                        // b*T + t
  float inv = 1.f / Lfin[row];
  float4 o = ((const float4*)Ofin)[idx];
  float4 res = {o.x * inv, o.y * inv, o.z * inv, o.w * inv};
  ((float4*)out)[idx] = res;
}

extern "C" void kernel_launch(void* const* d_in, const int* in_sizes, int n_in,
                              void* d_out, int out_size, void* d_ws, size_t ws_size,
                              hipStream_t stream) {
  const float* x = (const float*)d_in[0];
  const float* Wk = (const float*)d_in[1];
  const float* Wq = (const float*)d_in[2];
  const float* Wv = (const float*)d_in[3];
  float* out = (float*)d_out;
  char* ws = (char*)d_ws;
  // ws: Wtf[192*1024]bf16 | qb[4][4096][64]bf16 | Kf[4][64][4096]bf16 | Vf same
  //     | Ofin[4][4096][64]f32 | Lfin[4][4096]f32  (Ofin+Lfin contiguous, zeroed)
  __hip_bfloat16* Wtf = (__hip_bfloat16*)ws;
  __hip_bfloat16* qb = (__hip_bfloat16*)(ws + 393216);
  __hip_bfloat16* Kf = (__hip_bfloat16*)(ws + 2490368);
  __hip_bfloat16* Vf = (__hip_bfloat16*)(ws + 4587520);
  float* Ofin = (float*)(ws + 6684672);
  float* Lfin = (float*)(ws + 6684672 + 4194304);

  hipMemsetAsync(Ofin, 0, 4194304 + 65536, stream);  // graph-capture safe
  hipLaunchKernelGGL(wtrans_kernel, dim3(768), dim3(256), 0, stream, Wk, Wq, Wv, Wtf);
  hipLaunchKernelGGL(proj_kernel, dim3(1024), dim3(256), 0, stream, x, Wtf, qb, Kf, Vf);
  hipLaunchKernelGGL(fa_pass1, dim3(1152), dim3(256), 0, stream, qb, Kf, Vf, Ofin, Lfin);
  hipLaunchKernelGGL(fa_norm, dim3(1024), dim3(256), 0, stream, Ofin, Lfin, out);
}